// Round 8
// baseline (407.302 us; speedup 1.0000x reference)
//
#include <hip/hip_runtime.h>
#include <math.h>

#define FHW   32
#define NA    9
#define NBOX  9216          // 32*32*9
#define C1    256
#define C2    512
#define KTOT  2304          // 256*9
#define KS    8             // split-K (hp = 16.8 MB, stays L2-resident; KS=16 thrashed, r6)
#define KCH   288
#define CAP   64            // max stored in-neighbors per box
#define ECAP  12288         // LDS CSR edge capacity (overflow -> global fallback)
#define ROUNDS 96
#define NBLK  512           // MUST equal launch grid; 2 blocks/CU co-resident

struct AnchorWH { float w[NA]; float h[NA]; };

// ---------------- workspace layout (bytes) ----------------
#define FP_OFF    0u                      // padded feature 256*34*34 f32
#define WT_OFF    1183744u                // transposed weights 2304*512 f32
#define BOX_OFF   5902336u                // boxes 9216*4 f32
#define SC_OFF    6049792u                // scores 9216 f32
#define VL_OFF    6086656u                // vlist 9216 u32
#define DEG_OFF   6123520u                // deg 9216 u32
#define KEEP_OFF  6160384u                // keep 9216 u32
#define NV_OFF    6197248u                // valid count
#define BAR_OFF   6197376u                // grid-barrier counter (memset to 0 each call)
#define ADJ_OFF   6197504u                // adj 9216*CAP u16
#define HP_OFF    7377152u                // split-K partials KS*1024*512 f32 = 16.8 MB

// ---------------- LDS union (max = peel, 52.1 KB -> 2..3 blocks/CU) --------
struct SmemPrep  { float tile[32][33]; };
struct SmemGemm  { float As[16][64]; float Bs[16][128]; };
struct SmemHeads { float hrow[2][C2]; float arr[2][45]; };
struct SmemAdj   { float4 ub[128]; float4 vb[128]; float us[128]; float vs[128]; int uo[128]; int vo[128]; };
struct SmemPeel  {
    unsigned short offL[NBOX + 2];   // 18436
    unsigned char  st[NBOX];         // 9216
    unsigned short csr[ECAP];        // 24576
    unsigned int   scratch[256];     // 1024
    unsigned char  flags[ROUNDS];    // 96
};
union SmemU { SmemPrep p; SmemGemm g; SmemHeads h; SmemAdj a; SmemPeel e; };

// Software grid barrier: monotone counter, device-scope atomics, phase target.
// All NBLK blocks are co-resident (see capacity arithmetic above) -> no deadlock.
__device__ __forceinline__ void gbar(unsigned int* cnt, unsigned int phase) {
    __syncthreads();
    if (threadIdx.x == 0) {
        __threadfence();                           // release prior writes
        atomicAdd(cnt, 1u);
        const unsigned int target = NBLK * phase;
        while (atomicAdd(cnt, 0u) < target)        // device-scope atomic poll
            __builtin_amdgcn_s_sleep(15);
        __threadfence();                           // acquire
    }
    __syncthreads();
}

// ---------------------------------------------------------------------------
// Single persistent kernel: prep -> gemm -> heads -> adj -> peel -> out.
// ---------------------------------------------------------------------------
__global__ __launch_bounds__(256, 2) void k_all(const float* __restrict__ fin,
                                                const float* __restrict__ w1,
                                                const float* __restrict__ b1,
                                                const float* __restrict__ w2,
                                                const float* __restrict__ b2,
                                                const float* __restrict__ w3,
                                                const float* __restrict__ b3,
                                                float* __restrict__ out,
                                                char* __restrict__ ws,
                                                AnchorWH awh) {
    __shared__ SmemU sm;

    float*          Fp    = (float*)(ws + FP_OFF);
    float*          Wt    = (float*)(ws + WT_OFF);
    float*          boxes = (float*)(ws + BOX_OFF);
    float*          sc    = (float*)(ws + SC_OFF);
    unsigned int*   vlist = (unsigned int*)(ws + VL_OFF);
    unsigned int*   deg   = (unsigned int*)(ws + DEG_OFF);
    unsigned int*   keepG = (unsigned int*)(ws + KEEP_OFF);
    unsigned int*   nvp   = (unsigned int*)(ws + NV_OFF);
    unsigned int*   bar   = (unsigned int*)(ws + BAR_OFF);
    unsigned short* adjG  = (unsigned short*)(ws + ADJ_OFF);
    float*          hp    = (float*)(ws + HP_OFF);

    const int t   = threadIdx.x;
    const int gid = blockIdx.x * 256 + t;

    // ================= phase 0: pad feature, zero state, transpose weights ==
    for (int idx = gid; idx < 256 * 34 * 34; idx += NBLK * 256) {
        int c   = idx / 1156;
        int rem = idx - c * 1156;
        int yy  = rem / 34;
        int xx  = rem - yy * 34;
        float v = 0.f;
        if (yy >= 1 && yy <= 32 && xx >= 1 && xx <= 32)
            v = fin[c * 1024 + (yy - 1) * 32 + (xx - 1)];
        Fp[idx] = v;
    }
    if (gid < NBOX) { deg[gid] = 0u; keepG[gid] = 0u; }
    if (gid == 0)   *nvp = 0u;
    {
        const int r0 = t >> 5, c = t & 31;
        for (int tb = blockIdx.x; tb < 1152; tb += NBLK) {   // 72 x 16 tiles
            int k0  = (tb % 72) * 32;
            int oc0 = (tb / 72) * 32;
            #pragma unroll
            for (int i = 0; i < 4; ++i) {
                int r = r0 + 8 * i;                          // oc-local
                sm.p.tile[r][c] = w1[(oc0 + r) * KTOT + k0 + c];
            }
            __syncthreads();
            #pragma unroll
            for (int i = 0; i < 4; ++i) {
                int kk = r0 + 8 * i;                         // k-local
                Wt[(k0 + kk) * C2 + oc0 + c] = sm.p.tile[c][kk];
            }
            __syncthreads();
        }
    }
    gbar(bar, 1);

    // ================= phase 1: split-K fp32 GEMM (proven 44us config) =====
    {
        const int id = blockIdx.x;
        const int bx = id >> 5, g = id & 31;
        const int by = g >> 3, kz = g & 7;
        const int p0  = bx * 64;
        const int oc0 = by * 128;
        const int k0b = kz * KCH;
        const int ty = t >> 4, tx = t & 15;

        float acc[4][8];
        #pragma unroll
        for (int r = 0; r < 4; ++r)
            #pragma unroll
            for (int c = 0; c < 8; ++c) acc[r][c] = 0.f;

        for (int kt = 0; kt < KCH; kt += 16) {
            #pragma unroll
            for (int i = 0; i < 4; ++i) {
                int e  = t + 256 * i;
                int kk = e >> 6, pp = e & 63;
                int k   = k0b + kt + kk;
                int c   = k / 9;
                int kap = k - c * 9;
                int dy  = kap / 3;
                int dx  = kap - dy * 3;
                int p  = p0 + pp;
                int y  = p >> 5, x = p & 31;
                sm.g.As[kk][pp] = Fp[(c * 34 + y + dy) * 34 + x + dx];
            }
            #pragma unroll
            for (int i = 0; i < 2; ++i) {
                int e4 = t + 256 * i;
                int kk = e4 >> 5, c4 = e4 & 31;
                *(float4*)&sm.g.Bs[kk][c4 * 4] =
                    *(const float4*)&Wt[(k0b + kt + kk) * C2 + oc0 + c4 * 4];
            }
            __syncthreads();
            #pragma unroll
            for (int kk = 0; kk < 16; ++kk) {
                float a[4], b[8];
                *(float4*)&a[0] = *(const float4*)&sm.g.As[kk][ty * 4];
                *(float4*)&b[0] = *(const float4*)&sm.g.Bs[kk][tx * 4];
                *(float4*)&b[4] = *(const float4*)&sm.g.Bs[kk][tx * 4 + 64];
                #pragma unroll
                for (int r = 0; r < 4; ++r)
                    #pragma unroll
                    for (int c = 0; c < 8; ++c) acc[r][c] += a[r] * b[c];
            }
            __syncthreads();
        }
        #pragma unroll
        for (int r = 0; r < 4; ++r) {
            int p = p0 + ty * 4 + r;
            float* dst = hp + ((kz * 1024 + p) * C2 + oc0 + tx * 4);
            *(float4*)dst        = *(float4*)&acc[r][0];
            *(float4*)(dst + 64) = *(float4*)&acc[r][4];
        }
    }
    gbar(bar, 2);

    // ================= phase 2: heads (2 pixels/block) =====================
    {
        const int p0 = blockIdx.x * 2;
        #pragma unroll
        for (int px = 0; px < 2; ++px) {
            int p = p0 + px;
            #pragma unroll
            for (int i = 0; i < 2; ++i) {
                int c = t + 256 * i;
                float s = b1[c];
                #pragma unroll
                for (int ks = 0; ks < KS; ++ks) s += hp[(ks * 1024 + p) * C2 + c];
                sm.h.hrow[px][c] = fmaxf(s, 0.f);
            }
        }
        __syncthreads();

        const int w = t >> 6, lane = t & 63;
        for (int job = w; job < 90; job += 4) {
            int px = job / 45, j = job - px * 45;
            const float* wp = (j < 9) ? (w2 + j * C2) : (w3 + (j - 9) * C2);
            float s = 0.f;
            #pragma unroll
            for (int i = 0; i < 8; ++i)
                s += sm.h.hrow[px][lane + 64 * i] * wp[lane + 64 * i];
            #pragma unroll
            for (int d = 1; d < 64; d <<= 1) s += __shfl_xor(s, d, 64);
            if (lane == 0) sm.h.arr[px][j] = s;
        }
        __syncthreads();

        if (t < 18) {
            int px = t / 9, a = t - px * 9;
            int p = p0 + px;
            float logit = sm.h.arr[px][a] + b2[a];
            float score = 1.f / (1.f + expf(-logit));
            float o0 = sm.h.arr[px][9 + a * 4 + 0] + b3[a * 4 + 0];
            float o1 = sm.h.arr[px][9 + a * 4 + 1] + b3[a * 4 + 1];
            float o2 = sm.h.arr[px][9 + a * 4 + 2] + b3[a * 4 + 2];
            float o3 = sm.h.arr[px][9 + a * 4 + 3] + b3[a * 4 + 3];
            int y = p >> 5, x = p & 31;
            float ax = (x + 0.5f) * 16.f, ay = (y + 0.5f) * 16.f;
            float aw = awh.w[a], ah = awh.h[a];
            float cx = ax + o0 * aw;
            float cy = ay + o1 * ah;
            float bw = aw * expf(o2);
            float bh = ah * expf(o3);
            float x1 = fminf(fmaxf(cx - bw * 0.5f, 0.f), 512.f);
            float y1 = fminf(fmaxf(cy - bh * 0.5f, 0.f), 512.f);
            float x2 = fminf(fmaxf(cx + bw * 0.5f, 0.f), 512.f);
            float y2 = fminf(fmaxf(cy + bh * 0.5f, 0.f), 512.f);
            int n = p * 9 + a;
            float4 bx4; bx4.x = x1; bx4.y = y1; bx4.z = x2; bx4.w = y2;
            ((float4*)boxes)[n] = bx4;
            sc[n] = score;
            bool valid = (x2 - x1 >= 0.001f) && (y2 - y1 >= 0.001f) && (score >= 0.5f);
            if (valid) {
                unsigned int ci = atomicAdd(nvp, 1u);
                vlist[ci] = (unsigned int)n;
            }
        }
    }
    gbar(bar, 3);

    // ================= phase 3: sparse adjacency ===========================
    {
        const int Nv = (int)*nvp;
        const int T  = (Nv + 127) / 128;
        const int nTiles = T * (T + 1) / 2;
        for (int b = blockIdx.x; b < nTiles; b += NBLK) {
            int tv = (int)(sqrtf(2.f * b + 0.25f) - 0.5f);
            while ((tv + 1) * (tv + 2) / 2 <= b) tv++;
            while (tv * (tv + 1) / 2 > b) tv--;
            int tu = b - tv * (tv + 1) / 2;

            if (t < 128) {
                int gi = tu * 128 + t;
                if (gi < Nv) {
                    int n = (int)vlist[gi];
                    sm.a.ub[t] = ((const float4*)boxes)[n];
                    sm.a.us[t] = sc[n]; sm.a.uo[t] = n;
                } else sm.a.us[t] = -1.f;
            } else {
                int tt = t - 128;
                int gj = tv * 128 + tt;
                if (gj < Nv) {
                    int n = (int)vlist[gj];
                    sm.a.vb[tt] = ((const float4*)boxes)[n];
                    sm.a.vs[tt] = sc[n]; sm.a.vo[tt] = n;
                } else sm.a.vs[tt] = -1.f;
            }
            __syncthreads();

            for (int s = 0; s < 64; ++s) {
                int q  = t + 256 * s;          // 16384 pairs
                int i  = q >> 7, jj = q & 127;
                if (tu == tv && i >= jj) continue;
                float su = sm.a.us[i], sv = sm.a.vs[jj];
                if (su < 0.f || sv < 0.f) continue;
                float4 bu = sm.a.ub[i], bv = sm.a.vb[jj];
                float au = (bu.z - bu.x) * (bu.w - bu.y);
                float av = (bv.z - bv.x) * (bv.w - bv.y);
                float ix1 = fmaxf(bu.x, bv.x), iy1 = fmaxf(bu.y, bv.y);
                float ix2 = fminf(bu.z, bv.z), iy2 = fminf(bu.w, bv.w);
                float inter = fmaxf(ix2 - ix1, 0.f) * fmaxf(iy2 - iy1, 0.f);
                float uni = au + av - inter;
                float iou = inter / fmaxf(uni, 1e-9f);
                if (iou > 0.7f) {
                    int gi = tu * 128 + i, gj = tv * 128 + jj;
                    bool uHigh = (su > sv) || (su == sv && sm.a.uo[i] < sm.a.vo[jj]);
                    int lower = uHigh ? gj : gi;
                    int upper = uHigh ? gi : gj;
                    unsigned int slot = atomicAdd(&deg[lower], 1u);
                    if (slot < CAP) adjG[lower * CAP + slot] = (unsigned short)upper;
                }
            }
            __syncthreads();
        }
    }
    gbar(bar, 4);

    // ================= phase 4: MIS peel (block 0 only) ====================
    if (blockIdx.x == 0) {
        const int Nv = (int)*nvp;
        const int chunk = (Nv + 255) / 256;          // <= 36 (< 64-bit mask)
        const int i0 = t * chunk;
        const int i1 = (i0 + chunk < Nv) ? (i0 + chunk) : Nv;

        if (t < ROUNDS) sm.e.flags[t] = 0;

        unsigned int lsum = 0;
        for (int i = i0; i < i1; ++i) {
            unsigned int d = deg[i];
            if (d > CAP) d = CAP;
            sm.e.st[i] = (unsigned char)d;
            lsum += d;
        }
        sm.e.scratch[t] = lsum;
        __syncthreads();
        for (int ofs = 1; ofs < 256; ofs <<= 1) {    // Hillis-Steele inclusive
            unsigned int v = (t >= ofs) ? sm.e.scratch[t - ofs] : 0u;
            __syncthreads();
            sm.e.scratch[t] += v;
            __syncthreads();
        }
        if (t == 255) {
            unsigned int tot = sm.e.scratch[255];
            sm.e.offL[Nv] = (unsigned short)(tot < ECAP ? tot : ECAP);
        }
        unsigned long long amask = 0ull;
        {
            unsigned int off = sm.e.scratch[t] - lsum;
            for (int i = i0; i < i1; ++i) {
                unsigned int o = (off < ECAP) ? off : ECAP;
                sm.e.offL[i] = (unsigned short)o;
                int d = sm.e.st[i];
                int ld = (int)ECAP - (int)o; if (ld > d) ld = d; if (ld < 0) ld = 0;
                for (int s = 0; s < ld; ++s)
                    sm.e.csr[o + s] = adjG[i * CAP + s];
                off += d;
                if (d == 0) sm.e.st[i] = 1;
                else { sm.e.st[i] = 0; amask |= 1ull << (i - i0); }
            }
        }
        __syncthreads();

        for (int r = 0; r < ROUNDS; ++r) {
            bool any = false;
            unsigned long long m = amask;
            while (m) {
                int b = __builtin_ctzll(m); m &= m - 1;
                int i = i0 + b;
                int o = sm.e.offL[i], on = sm.e.offL[i + 1];
                int d, ld;
                if (on < ECAP) { d = on - o; ld = d; }
                else {
                    unsigned int dg = deg[i]; d = (dg > CAP) ? CAP : (int)dg;
                    ld = (int)ECAP - o; if (ld < 0) ld = 0; if (ld > d) ld = d;
                }
                bool kseen = false, useen = false;
                for (int s = 0; s < d; ++s) {
                    int j = (s < ld) ? (int)sm.e.csr[o + s] : (int)adjG[i * CAP + s];
                    unsigned char v = sm.e.st[j];
                    kseen |= (v == 1);
                    useen |= (v == 0);
                }
                if (kseen)       { sm.e.st[i] = 2; any = true; amask &= ~(1ull << b); }
                else if (!useen) { sm.e.st[i] = 1; any = true; amask &= ~(1ull << b); }
            }
            if (any) sm.e.flags[r] = 1;
            __syncthreads();
            if (!sm.e.flags[r]) break;
        }

        for (int i = i0; i < i1; ++i)
            if (sm.e.st[i] == 1) keepG[vlist[i]] = 1u;
    }
    gbar(bar, 5);

    // ================= phase 5: masked output write ========================
    if (gid < NBOX) {
        float k = keepG[gid] ? 1.f : 0.f;
        float4 b = ((const float4*)boxes)[gid];
        out[gid * 5 + 0] = b.x * k;
        out[gid * 5 + 1] = b.y * k;
        out[gid * 5 + 2] = b.z * k;
        out[gid * 5 + 3] = b.w * k;
        out[gid * 5 + 4] = sc[gid] * k;
    }
}

// ---------------------------------------------------------------------------
extern "C" void kernel_launch(void* const* d_in, const int* in_sizes, int n_in,
                              void* d_out, int out_size, void* d_ws, size_t ws_size,
                              hipStream_t stream) {
    const float* fin = (const float*)d_in[0];
    const float* w1  = (const float*)d_in[1];
    const float* b1  = (const float*)d_in[2];
    const float* w2  = (const float*)d_in[3];
    const float* b2  = (const float*)d_in[4];
    const float* w3  = (const float*)d_in[5];
    const float* b3  = (const float*)d_in[6];
    float* out = (float*)d_out;
    char*  ws  = (char*)d_ws;

    AnchorWH awh;
    {
        const double sizes[3]  = {32.0, 64.0, 128.0};
        const double ratios[3] = {0.5, 1.0, 2.0};
        for (int si = 0; si < 3; ++si)
            for (int ri = 0; ri < 3; ++ri) {
                awh.w[si * 3 + ri] = (float)(sizes[si] / sqrt(ratios[ri]));
                awh.h[si * 3 + ri] = (float)(sizes[si] * sqrt(ratios[ri]));
            }
    }

    // zero the grid-barrier counter (ws is re-poisoned 0xAA before every call)
    hipMemsetAsync(ws + BAR_OFF, 0, 64, stream);
    k_all<<<dim3(NBLK), dim3(256), 0, stream>>>(fin, w1, b1, w2, b2, w3, b3,
                                                out, ws, awh);
}

// Round 10
// 264.635 us; speedup vs baseline: 1.5391x; 1.5391x over previous
//
#include <hip/hip_runtime.h>
#include <math.h>

#define FHW   32
#define NA    9
#define NBOX  9216          // 32*32*9
#define C1    256
#define C2    512
#define KTOT  2304          // 256*9
#define KS    8             // split-K (hp = 16.8 MB, L2-resident; KS=16 thrashed, r6)
#define KCH   288
#define CAP   64            // max stored in-neighbors per box
#define ECAP  12288         // LDS CSR edge capacity (overflow -> global fallback)
#define ROUNDS 96
#define NBLK  512           // MUST equal launch grid; <=2 blocks/CU -> co-resident (proven r8)
#define NSUB  16            // barrier sub-counters
#define SUBQ  (NBLK / NSUB) // 32 blocks per sub-counter

struct AnchorWH { float w[NA]; float h[NA]; };

// ---------------- workspace layout (bytes) ----------------
#define BOX_OFF   0u          // boxes 9216*4 f32 = 147456
#define SC_OFF    147456u     // scores 9216 f32
#define VL_OFF    184320u     // vlist 9216 u32
#define DEG_OFF   221184u     // deg 9216 u32
#define NV_OFF    258048u     // valid count (256 B slot)
#define BAR_OFF   258304u     // barrier counters (2048 B, memset 0 each call)
#define ADJ_OFF   260352u     // adj 9216*CAP u16 = 1179648
#define HP_OFF    1440000u    // split-K partials KS*1024*512 f32 = 16.8 MB (tot ~18.2 MB)

// ---------------- LDS union (max = peel ~53.3 KB -> 2 blocks/CU) -----------
struct SmemGemm  { float As[16][64]; float Bs[16][128]; };
struct SmemHeads { float hrow[2][C2]; float arr[2][45]; };
struct SmemAdj   { float4 ub[128]; float4 vb[128]; float us[128]; float vs[128]; int uo[128]; int vo[128]; };
struct SmemPeel  {
    unsigned short offL[NBOX + 2];   // 18436
    unsigned char  st[NBOX];         // 9216
    unsigned short csr[ECAP];        // 24576
    unsigned int   scratch[256];     // 1024
    unsigned char  flags[ROUNDS];    // 96
};
union SmemU { SmemGemm g; SmemHeads h; SmemAdj a; SmemPeel e; };

// ---------------- software grid barrier v2 ---------------------------------
// r8 post-mortem: RMW polling convoyed at the coherence point (~50 us/barrier).
// v2: hierarchical arrivals (16 lines x 32 RMWs, parallel), relaxed-LOAD poll,
// __threadfence (agent-scope) at arrive/exit only. Monotone counters.
__device__ __forceinline__ void gbar_arrive(char* base, int phase) {
    __syncthreads();
    if (threadIdx.x == 0) {
        __threadfence();                               // release prior writes
        unsigned int* sub =
            (unsigned int*)(base + (blockIdx.x & (NSUB - 1)) * 64);
        unsigned int old = __hip_atomic_fetch_add(sub, 1u, __ATOMIC_RELAXED,
                                                  __HIP_MEMORY_SCOPE_AGENT);
        if (old == (unsigned int)(SUBQ * phase - 1)) {
            unsigned int* root = (unsigned int*)(base + 1024);
            __hip_atomic_fetch_add(root, 1u, __ATOMIC_RELAXED,
                                   __HIP_MEMORY_SCOPE_AGENT);
        }
    }
}
__device__ __forceinline__ void gbar_wait(char* base, int phase) {
    if (threadIdx.x == 0) {
        unsigned int* root = (unsigned int*)(base + 1024);
        while (__hip_atomic_load(root, __ATOMIC_RELAXED,
                                 __HIP_MEMORY_SCOPE_AGENT) <
               (unsigned int)(NSUB * phase))
            __builtin_amdgcn_s_sleep(31);
        __threadfence();                               // acquire
    }
    __syncthreads();
}

// ---------------------------------------------------------------------------
// Single persistent kernel: gemm -> heads -> adj -> peel+out. 3 barriers.
// ---------------------------------------------------------------------------
__global__ __launch_bounds__(256, 2) void k_all(const float* __restrict__ fin,
                                                const float* __restrict__ w1,
                                                const float* __restrict__ b1,
                                                const float* __restrict__ w2,
                                                const float* __restrict__ b2,
                                                const float* __restrict__ w3,
                                                const float* __restrict__ b3,
                                                float* __restrict__ out,
                                                char* __restrict__ ws,
                                                AnchorWH awh) {
    __shared__ SmemU sm;

    float*          boxes = (float*)(ws + BOX_OFF);
    float*          sc    = (float*)(ws + SC_OFF);
    unsigned int*   vlist = (unsigned int*)(ws + VL_OFF);
    unsigned int*   deg   = (unsigned int*)(ws + DEG_OFF);
    unsigned int*   nvp   = (unsigned int*)(ws + NV_OFF);
    char*           bar   = ws + BAR_OFF;
    unsigned short* adjG  = (unsigned short*)(ws + ADJ_OFF);
    float*          hp    = (float*)(ws + HP_OFF);

    const int t   = threadIdx.x;
    const int gid = blockIdx.x * 256 + t;

    // ================= phase 1: split-K fp32 GEMM (direct in/weight loads) ==
    // A gathered from fin with bounds-check (no padded copy); B staged from
    // w1 [512][2304] directly (64B-segment reads, L2-resident).
    if (gid < NBOX) deg[gid] = 0u;
    if (gid == 0)   *nvp = 0u;
    {
        const int id = blockIdx.x;
        const int bx = id >> 5, g = id & 31;
        const int by = g >> 3, kz = g & 7;
        const int p0  = bx * 64;
        const int oc0 = by * 128;
        const int k0b = kz * KCH;
        const int ty = t >> 4, tx = t & 15;
        const int bj = t >> 1, bkh = (t & 1) * 8;   // B staging map

        float acc[4][8];
        #pragma unroll
        for (int r = 0; r < 4; ++r)
            #pragma unroll
            for (int c = 0; c < 8; ++c) acc[r][c] = 0.f;

        for (int kt = 0; kt < KCH; kt += 16) {
            // A: im2col gather from fin, 16x64, 4 elems/thread
            #pragma unroll
            for (int i = 0; i < 4; ++i) {
                int e  = t + 256 * i;
                int kk = e >> 6, pp = e & 63;
                int k   = k0b + kt + kk;
                int c   = k / 9;
                int kap = k - c * 9;
                int dy  = kap / 3;
                int dx  = kap - dy * 3;
                int p  = p0 + pp;
                int yy = (p >> 5) + dy - 1;
                int xx = (p & 31) + dx - 1;
                float v = 0.f;
                if (yy >= 0 && yy < 32 && xx >= 0 && xx < 32)
                    v = fin[c * 1024 + yy * 32 + xx];
                sm.g.As[kk][pp] = v;
            }
            // B: 16x128 from w1, 8 contiguous k per thread (2x float4)
            {
                const float* src = w1 + (oc0 + bj) * KTOT + k0b + kt + bkh;
                float4 v0 = *(const float4*)src;
                float4 v1 = *(const float4*)(src + 4);
                sm.g.Bs[bkh + 0][bj] = v0.x; sm.g.Bs[bkh + 1][bj] = v0.y;
                sm.g.Bs[bkh + 2][bj] = v0.z; sm.g.Bs[bkh + 3][bj] = v0.w;
                sm.g.Bs[bkh + 4][bj] = v1.x; sm.g.Bs[bkh + 5][bj] = v1.y;
                sm.g.Bs[bkh + 6][bj] = v1.z; sm.g.Bs[bkh + 7][bj] = v1.w;
            }
            __syncthreads();
            #pragma unroll
            for (int kk = 0; kk < 16; ++kk) {
                float a[4], b[8];
                *(float4*)&a[0] = *(const float4*)&sm.g.As[kk][ty * 4];
                *(float4*)&b[0] = *(const float4*)&sm.g.Bs[kk][tx * 4];
                *(float4*)&b[4] = *(const float4*)&sm.g.Bs[kk][tx * 4 + 64];
                #pragma unroll
                for (int r = 0; r < 4; ++r)
                    #pragma unroll
                    for (int c = 0; c < 8; ++c) acc[r][c] += a[r] * b[c];
            }
            __syncthreads();
        }
        #pragma unroll
        for (int r = 0; r < 4; ++r) {
            int p = p0 + ty * 4 + r;
            float* dst = hp + ((kz * 1024 + p) * C2 + oc0 + tx * 4);
            *(float4*)dst        = *(float4*)&acc[r][0];
            *(float4*)(dst + 64) = *(float4*)&acc[r][4];
        }
    }
    gbar_arrive(bar, 1); gbar_wait(bar, 1);

    // ================= phase 2: heads (2 pixels/block) =====================
    {
        const int p0 = blockIdx.x * 2;
        #pragma unroll
        for (int px = 0; px < 2; ++px) {
            int p = p0 + px;
            #pragma unroll
            for (int i = 0; i < 2; ++i) {
                int c = t + 256 * i;
                float s = b1[c];
                #pragma unroll
                for (int ks = 0; ks < KS; ++ks) s += hp[(ks * 1024 + p) * C2 + c];
                sm.h.hrow[px][c] = fmaxf(s, 0.f);
            }
        }
        __syncthreads();

        const int w = t >> 6, lane = t & 63;
        for (int job = w; job < 90; job += 4) {
            int px = job / 45, j = job - px * 45;
            const float* wp = (j < 9) ? (w2 + j * C2) : (w3 + (j - 9) * C2);
            float s = 0.f;
            #pragma unroll
            for (int i = 0; i < 8; ++i)
                s += sm.h.hrow[px][lane + 64 * i] * wp[lane + 64 * i];
            #pragma unroll
            for (int d = 1; d < 64; d <<= 1) s += __shfl_xor(s, d, 64);
            if (lane == 0) sm.h.arr[px][j] = s;
        }
        __syncthreads();

        if (t < 18) {
            int px = t / 9, a = t - px * 9;
            int p = p0 + px;
            float logit = sm.h.arr[px][a] + b2[a];
            float score = 1.f / (1.f + expf(-logit));
            float o0 = sm.h.arr[px][9 + a * 4 + 0] + b3[a * 4 + 0];
            float o1 = sm.h.arr[px][9 + a * 4 + 1] + b3[a * 4 + 1];
            float o2 = sm.h.arr[px][9 + a * 4 + 2] + b3[a * 4 + 2];
            float o3 = sm.h.arr[px][9 + a * 4 + 3] + b3[a * 4 + 3];
            int y = p >> 5, x = p & 31;
            float ax = (x + 0.5f) * 16.f, ay = (y + 0.5f) * 16.f;
            float aw = awh.w[a], ah = awh.h[a];
            float cx = ax + o0 * aw;
            float cy = ay + o1 * ah;
            float bw = aw * expf(o2);
            float bh = ah * expf(o3);
            float x1 = fminf(fmaxf(cx - bw * 0.5f, 0.f), 512.f);
            float y1 = fminf(fmaxf(cy - bh * 0.5f, 0.f), 512.f);
            float x2 = fminf(fmaxf(cx + bw * 0.5f, 0.f), 512.f);
            float y2 = fminf(fmaxf(cy + bh * 0.5f, 0.f), 512.f);
            int n = p * 9 + a;
            float4 bx4; bx4.x = x1; bx4.y = y1; bx4.z = x2; bx4.w = y2;
            ((float4*)boxes)[n] = bx4;
            sc[n] = score;
            bool valid = (x2 - x1 >= 0.001f) && (y2 - y1 >= 0.001f) && (score >= 0.5f);
            if (valid) {
                unsigned int ci = atomicAdd(nvp, 1u);
                vlist[ci] = (unsigned int)n;
            }
        }
    }
    gbar_arrive(bar, 2); gbar_wait(bar, 2);

    // ================= phase 3: sparse adjacency ===========================
    {
        const int Nv = (int)*nvp;
        const int T  = (Nv + 127) / 128;
        const int nTiles = T * (T + 1) / 2;
        for (int b = blockIdx.x; b < nTiles; b += NBLK) {
            int tv = (int)(sqrtf(2.f * b + 0.25f) - 0.5f);
            while ((tv + 1) * (tv + 2) / 2 <= b) tv++;
            while (tv * (tv + 1) / 2 > b) tv--;
            int tu = b - tv * (tv + 1) / 2;

            if (t < 128) {
                int gi = tu * 128 + t;
                if (gi < Nv) {
                    int n = (int)vlist[gi];
                    sm.a.ub[t] = ((const float4*)boxes)[n];
                    sm.a.us[t] = sc[n]; sm.a.uo[t] = n;
                } else sm.a.us[t] = -1.f;
            } else {
                int tt = t - 128;
                int gj = tv * 128 + tt;
                if (gj < Nv) {
                    int n = (int)vlist[gj];
                    sm.a.vb[tt] = ((const float4*)boxes)[n];
                    sm.a.vs[tt] = sc[n]; sm.a.vo[tt] = n;
                } else sm.a.vs[tt] = -1.f;
            }
            __syncthreads();

            for (int s = 0; s < 64; ++s) {
                int q  = t + 256 * s;          // 16384 pairs
                int i  = q >> 7, jj = q & 127;
                if (tu == tv && i >= jj) continue;
                float su = sm.a.us[i], sv = sm.a.vs[jj];
                if (su < 0.f || sv < 0.f) continue;
                float4 bu = sm.a.ub[i], bv = sm.a.vb[jj];
                float au = (bu.z - bu.x) * (bu.w - bu.y);
                float av = (bv.z - bv.x) * (bv.w - bv.y);
                float ix1 = fmaxf(bu.x, bv.x), iy1 = fmaxf(bu.y, bv.y);
                float ix2 = fminf(bu.z, bv.z), iy2 = fminf(bu.w, bv.w);
                float inter = fmaxf(ix2 - ix1, 0.f) * fmaxf(iy2 - iy1, 0.f);
                float uni = au + av - inter;
                float iou = inter / fmaxf(uni, 1e-9f);
                if (iou > 0.7f) {
                    int gi = tu * 128 + i, gj = tv * 128 + jj;
                    bool uHigh = (su > sv) || (su == sv && sm.a.uo[i] < sm.a.vo[jj]);
                    int lower = uHigh ? gj : gi;
                    int upper = uHigh ? gi : gj;
                    unsigned int slot = atomicAdd(&deg[lower], 1u);
                    if (slot < CAP) adjG[lower * CAP + slot] = (unsigned short)upper;
                }
            }
            __syncthreads();
        }
    }
    gbar_arrive(bar, 3);
    if (blockIdx.x != 0) return;     // only block 0 needs barrier-3 completion
    gbar_wait(bar, 3);

    // ================= phase 4 (block 0): MIS peel + output write ==========
    {
        const int Nv = (int)*nvp;
        const int chunk = (Nv + 255) / 256;          // <= 36 (64-bit mask)
        const int i0 = t * chunk;
        const int i1 = (i0 + chunk < Nv) ? (i0 + chunk) : Nv;

        if (t < ROUNDS) sm.e.flags[t] = 0;

        unsigned int lsum = 0;
        for (int i = i0; i < i1; ++i) {
            unsigned int d = deg[i];
            if (d > CAP) d = CAP;
            sm.e.st[i] = (unsigned char)d;
            lsum += d;
        }
        sm.e.scratch[t] = lsum;
        __syncthreads();
        for (int ofs = 1; ofs < 256; ofs <<= 1) {    // Hillis-Steele inclusive
            unsigned int v = (t >= ofs) ? sm.e.scratch[t - ofs] : 0u;
            __syncthreads();
            sm.e.scratch[t] += v;
            __syncthreads();
        }
        if (t == 255) {
            unsigned int tot = sm.e.scratch[255];
            sm.e.offL[Nv] = (unsigned short)(tot < ECAP ? tot : ECAP);
        }
        unsigned long long amask = 0ull;
        {
            unsigned int off = sm.e.scratch[t] - lsum;
            for (int i = i0; i < i1; ++i) {
                unsigned int o = (off < ECAP) ? off : ECAP;
                sm.e.offL[i] = (unsigned short)o;
                int d = sm.e.st[i];
                int ld = (int)ECAP - (int)o; if (ld > d) ld = d; if (ld < 0) ld = 0;
                for (int s = 0; s < ld; ++s)
                    sm.e.csr[o + s] = adjG[i * CAP + s];
                off += d;
                if (d == 0) sm.e.st[i] = 1;
                else { sm.e.st[i] = 0; amask |= 1ull << (i - i0); }
            }
        }
        __syncthreads();

        for (int r = 0; r < ROUNDS; ++r) {
            bool any = false;
            unsigned long long m = amask;
            while (m) {
                int b = __builtin_ctzll(m); m &= m - 1;
                int i = i0 + b;
                int o = sm.e.offL[i], on = sm.e.offL[i + 1];
                int d, ld;
                if (on < ECAP) { d = on - o; ld = d; }
                else {
                    unsigned int dg = deg[i]; d = (dg > CAP) ? CAP : (int)dg;
                    ld = (int)ECAP - o; if (ld < 0) ld = 0; if (ld > d) ld = d;
                }
                bool kseen = false, useen = false;
                for (int s = 0; s < d; ++s) {
                    int j = (s < ld) ? (int)sm.e.csr[o + s] : (int)adjG[i * CAP + s];
                    unsigned char v = sm.e.st[j];
                    kseen |= (v == 1);
                    useen |= (v == 0);
                }
                if (kseen)       { sm.e.st[i] = 2; any = true; amask &= ~(1ull << b); }
                else if (!useen) { sm.e.st[i] = 1; any = true; amask &= ~(1ull << b); }
            }
            if (any) sm.e.flags[r] = 1;
            __syncthreads();
            if (!sm.e.flags[r]) break;
        }

        // zero-fill output, then scatter kept rows
        for (int m4 = t; m4 < NBOX * 5 / 4; m4 += 256) {
            float4 z; z.x = 0.f; z.y = 0.f; z.z = 0.f; z.w = 0.f;
            ((float4*)out)[m4] = z;
        }
        __syncthreads();
        for (int i = t; i < Nv; i += 256) {
            if (sm.e.st[i] == 1) {
                int n = (int)vlist[i];
                float4 b = ((const float4*)boxes)[n];
                out[n * 5 + 0] = b.x;
                out[n * 5 + 1] = b.y;
                out[n * 5 + 2] = b.z;
                out[n * 5 + 3] = b.w;
                out[n * 5 + 4] = sc[n];
            }
        }
    }
}

// ---------------------------------------------------------------------------
extern "C" void kernel_launch(void* const* d_in, const int* in_sizes, int n_in,
                              void* d_out, int out_size, void* d_ws, size_t ws_size,
                              hipStream_t stream) {
    const float* fin = (const float*)d_in[0];
    const float* w1  = (const float*)d_in[1];
    const float* b1  = (const float*)d_in[2];
    const float* w2  = (const float*)d_in[3];
    const float* b2  = (const float*)d_in[4];
    const float* w3  = (const float*)d_in[5];
    const float* b3  = (const float*)d_in[6];
    float* out = (float*)d_out;
    char*  ws  = (char*)d_ws;

    AnchorWH awh;
    {
        const double sizes[3]  = {32.0, 64.0, 128.0};
        const double ratios[3] = {0.5, 1.0, 2.0};
        for (int si = 0; si < 3; ++si)
            for (int ri = 0; ri < 3; ++ri) {
                awh.w[si * 3 + ri] = (float)(sizes[si] / sqrt(ratios[ri]));
                awh.h[si * 3 + ri] = (float)(sizes[si] * sqrt(ratios[ri]));
            }
    }

    // zero the barrier counters (ws is re-poisoned 0xAA before every call)
    (void)hipMemsetAsync(ws + BAR_OFF, 0, 2048, stream);
    k_all<<<dim3(NBLK), dim3(256), 0, stream>>>(fin, w1, b1, w2, b2, w3, b3,
                                                out, ws, awh);
}